// Round 1
// baseline (95.613 us; speedup 1.0000x reference)
//
#include <hip/hip_runtime.h>

#define KC   21      // num classes
#define BB   8       // batch
#define CC   256     // feat channels
#define HWP  65536   // 256*256 output pixels per image
#define SRC  4096    // 64*64 source pixels
#define CHUNKS 32
#define PCHUNK 128   // SRC / CHUNKS

// Phase 1: per-pixel argmax + gt match -> scatter bilinear weights into W[b,k,64,64]
__global__ void p1_classify_scatter(const float* __restrict__ preds,
                                    const int*   __restrict__ masks,
                                    float* __restrict__ Wmap,    // [B][K][SRC]
                                    float* __restrict__ counts)  // [B][K]
{
    int idx = blockIdx.x * blockDim.x + threadIdx.x;   // over B*HWP
    if (idx >= BB * HWP) return;
    int b  = idx >> 16;
    int hw = idx & (HWP - 1);

    const float* p = preds + (size_t)b * KC * HWP + hw;
    float best = p[0];
    int   bi   = 0;
#pragma unroll
    for (int k = 1; k < KC; ++k) {
        float v = p[(size_t)k * HWP];
        if (v > best) { best = v; bi = k; }   // strict > keeps first index (jnp.argmax)
    }

    int m = masks[idx];
    if (m == bi && (unsigned)m < KC) {
        int h = hw >> 8, w = hw & 255;
        // half-pixel bilinear, scale 4: src = (d+0.5)*0.25 - 0.5
        float sy = h * 0.25f - 0.375f;
        float sx = w * 0.25f - 0.375f;
        int y0 = (int)floorf(sy), x0 = (int)floorf(sx);
        float wy = sy - (float)y0, wx = sx - (float)x0;
        int y0c = y0 < 0 ? 0 : y0;
        int y1c = y0 + 1 > 63 ? 63 : y0 + 1;
        int x0c = x0 < 0 ? 0 : x0;
        int x1c = x0 + 1 > 63 ? 63 : x0 + 1;
        float* Wb = Wmap + (size_t)(b * KC + m) * SRC;
        atomicAdd(&Wb[y0c * 64 + x0c], (1.f - wy) * (1.f - wx));
        atomicAdd(&Wb[y0c * 64 + x1c], (1.f - wy) * wx);
        atomicAdd(&Wb[y1c * 64 + x0c], wy * (1.f - wx));
        atomicAdd(&Wb[y1c * 64 + x1c], wy * wx);
        atomicAdd(&counts[b * KC + m], 1.0f);
    }
}

// Phase 2: partial[b][chunk][k][c] = sum_{p in chunk} feats[b][c][p] * W[b][k][p]
__global__ void p2_contract(const float* __restrict__ feats,  // [B][C][SRC]
                            const float* __restrict__ Wmap,   // [B][K][SRC]
                            float* __restrict__ partial)      // [B][CHUNKS][K][C]
{
    int chunk = blockIdx.x;
    int b     = blockIdx.y;
    int c     = threadIdx.x;
    int p0    = chunk * PCHUNK;

    const float* f  = feats + (size_t)(b * CC + c) * SRC + p0;
    const float* Wb = Wmap  + (size_t)b * KC * SRC + p0;

    float acc[KC];
#pragma unroll
    for (int k = 0; k < KC; ++k) acc[k] = 0.f;

    for (int p = 0; p < PCHUNK; p += 4) {
        float4 fv = *reinterpret_cast<const float4*>(f + p);
#pragma unroll
        for (int k = 0; k < KC; ++k) {
            // wave-uniform address -> scalar loads / broadcast
            const float* wk = Wb + k * SRC + p;
            acc[k] += fv.x * wk[0] + fv.y * wk[1] + fv.z * wk[2] + fv.w * wk[3];
        }
    }

    float* out = partial + ((size_t)(b * CHUNKS + chunk) * KC) * CC + c;
#pragma unroll
    for (int k = 0; k < KC; ++k) out[(size_t)k * CC] = acc[k];
}

// Phase 3: proto[k][c] = (1/B) * sum_b (sum_chunk partial) / (counts[b][k] + eps)
__global__ void p3_finalize(const float* __restrict__ partial,
                            const float* __restrict__ counts,
                            float* __restrict__ out)
{
    int k = blockIdx.x;
    int c = threadIdx.x;
    float acc = 0.f;
    for (int b = 0; b < BB; ++b) {
        float s = 0.f;
        for (int ch = 0; ch < CHUNKS; ++ch)
            s += partial[((size_t)(b * CHUNKS + ch) * KC + k) * CC + c];
        acc += s / (counts[b * KC + k] + 1e-6f);
    }
    out[k * CC + c] = acc * (1.0f / BB);
}

extern "C" void kernel_launch(void* const* d_in, const int* in_sizes, int n_in,
                              void* d_out, int out_size, void* d_ws, size_t ws_size,
                              hipStream_t stream) {
    const float* feats = (const float*)d_in[0];   // [8,256,64,64]
    const float* preds = (const float*)d_in[1];   // [8,21,256,256]
    const int*   masks = (const int*)  d_in[2];   // [8,256,256]
    float* out = (float*)d_out;                   // [21,256]

    float* counts  = (float*)d_ws;                // 256 floats (168 used)
    float* Wmap    = counts + 256;                // B*K*SRC = 688128 floats
    float* partial = Wmap + BB * KC * SRC;        // B*CHUNKS*K*C = 1376256 floats

    // zero counts + W (accumulated via atomics each call)
    hipMemsetAsync(d_ws, 0, (256 + BB * KC * SRC) * sizeof(float), stream);

    p1_classify_scatter<<<(BB * HWP) / 256, 256, 0, stream>>>(preds, masks, Wmap, counts);
    p2_contract<<<dim3(CHUNKS, BB), CC, 0, stream>>>(feats, Wmap, partial);
    p3_finalize<<<KC, CC, 0, stream>>>(partial, counts, out);
}

// Round 2
// 55.081 us; speedup vs baseline: 1.7359x; 1.7359x over previous
//
#include <hip/hip_runtime.h>

#define KC   21      // num classes
#define BB   8       // batch
#define CC   256     // feat channels
#define HWP  65536   // 256*256 output pixels per image
#define SRC  4096    // 64*64 source pixels
#define CH   32      // p-chunks of 128
#define LDF  66      // padded LDS row stride for feats tile (bank-spread)

// ---------------- Phase 1: argmax + gt-match -> scatter bilinear weights ----
// 4 pixels per thread; all 21 class loads issued before the compare chain.
__global__ __launch_bounds__(256)
void p1_classify_scatter(const float* __restrict__ preds,
                         const int*   __restrict__ masks,
                         float* __restrict__ Wmap)    // [B][K][SRC]
{
    int idx = blockIdx.x * 256 + threadIdx.x;        // over B*HWP/4 = 131072
    int b   = idx >> 14;
    int hw4 = (idx & 16383) << 2;

    const float* pb = preds + (size_t)b * KC * HWP + hw4;
    float4 v[KC];
#pragma unroll
    for (int k = 0; k < KC; ++k)
        v[k] = *reinterpret_cast<const float4*>(pb + (size_t)k * HWP);

    int4 mm = *reinterpret_cast<const int4*>(masks + b * HWP + hw4);

    float bx = v[0].x, by = v[0].y, bz = v[0].z, bw = v[0].w;
    int   ix = 0, iy = 0, iz = 0, iw = 0;
#pragma unroll
    for (int k = 1; k < KC; ++k) {
        if (v[k].x > bx) { bx = v[k].x; ix = k; }
        if (v[k].y > by) { by = v[k].y; iy = k; }
        if (v[k].z > bz) { bz = v[k].z; iz = k; }
        if (v[k].w > bw) { bw = v[k].w; iw = k; }
    }

    int m[4]  = { mm.x, mm.y, mm.z, mm.w };
    int am[4] = { ix, iy, iz, iw };
#pragma unroll
    for (int j = 0; j < 4; ++j) {
        int mv = m[j];
        if (mv == am[j] && (unsigned)mv < KC) {
            int hw = hw4 + j;
            int h = hw >> 8, w = hw & 255;
            // half-pixel bilinear at 4x: src = (d+0.5)*0.25 - 0.5
            float sy = h * 0.25f - 0.375f;
            float sx = w * 0.25f - 0.375f;
            int y0 = (int)floorf(sy), x0 = (int)floorf(sx);
            float wy = sy - (float)y0, wx = sx - (float)x0;
            int y0c = y0 < 0 ? 0 : y0;
            int y1c = y0 + 1 > 63 ? 63 : y0 + 1;
            int x0c = x0 < 0 ? 0 : x0;
            int x1c = x0 + 1 > 63 ? 63 : x0 + 1;
            float* Wb = Wmap + (size_t)(b * KC + mv) * SRC;
            atomicAdd(&Wb[y0c * 64 + x0c], (1.f - wy) * (1.f - wx));
            atomicAdd(&Wb[y0c * 64 + x1c], (1.f - wy) * wx);
            atomicAdd(&Wb[y1c * 64 + x0c], wy * (1.f - wx));
            atomicAdd(&Wb[y1c * 64 + x1c], wy * wx);
        }
    }
}

// ---------------- Phase 2: sums[b,k,c] partial contraction via LDS ---------
// Block = (chunk of 128 p, b). Coalesced global reads; LDS-staged feats tile
// [256 c][66] (padded). W tile [21][128] read as uniform b128 broadcasts.
// Also emits per-chunk W row-sums (== per-class pixel counts, exact dyadics).
__global__ __launch_bounds__(256)
void p2_contract(const float* __restrict__ feats,    // [B][C][SRC]
                 const float* __restrict__ Wmap,     // [B][K][SRC]
                 float* __restrict__ partial,        // [B][CH][K][C]
                 float* __restrict__ partialw)       // [B][CH][K]
{
    __shared__ float fs[CC * LDF];    // 67.6 KB
    __shared__ float ws[KC * 128];    // 10.75 KB
    int chunk = blockIdx.x;           // 0..31
    int b     = blockIdx.y;
    int p0    = chunk * 128;
    int tid   = threadIdx.x;

    // stage W[21][128]
    for (int t = tid; t < KC * 32; t += 256) {
        int k = t >> 5, q = t & 31;
        float4 w4 = *reinterpret_cast<const float4*>(
            Wmap + (size_t)(b * KC + k) * SRC + p0 + q * 4);
        *reinterpret_cast<float4*>(ws + k * 128 + q * 4) = w4;
    }

    float acc[KC];
#pragma unroll
    for (int k = 0; k < KC; ++k) acc[k] = 0.f;

    int cg = tid >> 4;   // 0..15
    int pl = tid & 15;   // 0..15

    for (int s = 0; s < 2; ++s) {
        int ps = p0 + s * 64;
        __syncthreads();   // fs safe to overwrite (also fences W staging on s=0)
#pragma unroll
        for (int i = 0; i < 16; ++i) {
            int c = cg + i * 16;
            float4 f4 = *reinterpret_cast<const float4*>(
                feats + (size_t)(b * CC + c) * SRC + ps + pl * 4);
            float* d = fs + c * LDF + pl * 4;     // 8B-aligned always
            *reinterpret_cast<float2*>(d)     = make_float2(f4.x, f4.y);
            *reinterpret_cast<float2*>(d + 2) = make_float2(f4.z, f4.w);
        }
        __syncthreads();

        const float* frow  = fs + tid * LDF;
        const float* wbase = ws + s * 64;
#pragma unroll
        for (int p = 0; p < 64; p += 4) {
            float2 f01 = *reinterpret_cast<const float2*>(frow + p);
            float2 f23 = *reinterpret_cast<const float2*>(frow + p + 2);
#pragma unroll
            for (int k = 0; k < KC; ++k) {
                float4 w4 = *reinterpret_cast<const float4*>(wbase + k * 128 + p);
                acc[k] += f01.x * w4.x + f01.y * w4.y + f23.x * w4.z + f23.y * w4.w;
            }
        }
    }

    float* outp = partial + ((size_t)(b * CH + chunk) * KC) * CC + tid;
#pragma unroll
    for (int k = 0; k < KC; ++k) outp[(size_t)k * CC] = acc[k];

    __syncthreads();
    if (tid < KC) {
        float sw = 0.f;
        for (int p = 0; p < 128; ++p) sw += ws[tid * 128 + p];
        partialw[(b * CH + chunk) * KC + tid] = sw;   // exact class count contrib
    }
}

// ---------------- Phase 3: reduce chunks, normalize, batch-mean ------------
__global__ __launch_bounds__(256)
void p3_finalize(const float* __restrict__ partial,
                 const float* __restrict__ partialw,
                 float* __restrict__ out)             // [K][C], pre-zeroed
{
    int k   = blockIdx.x;   // 21
    int b   = blockIdx.y;   // 8
    int tid = threadIdx.x;  // c

    float s = 0.f;
    const float* base = partial + ((size_t)(b * CH) * KC + k) * CC + tid;
#pragma unroll 4
    for (int ch = 0; ch < CH; ++ch) s += base[(size_t)ch * KC * CC];

    __shared__ float wsh;
    if (tid < 64) {
        float w = (tid < CH) ? partialw[(b * CH + tid) * KC + k] : 0.f;
#pragma unroll
        for (int off = 32; off; off >>= 1) w += __shfl_down(w, off);
        if (tid == 0) wsh = w;
    }
    __syncthreads();

    float denom = 8.0f * (wsh + 1e-6f);
    atomicAdd(&out[k * CC + tid], s / denom);
}

extern "C" void kernel_launch(void* const* d_in, const int* in_sizes, int n_in,
                              void* d_out, int out_size, void* d_ws, size_t ws_size,
                              hipStream_t stream) {
    const float* feats = (const float*)d_in[0];   // [8,256,64,64]
    const float* preds = (const float*)d_in[1];   // [8,21,256,256]
    const int*   masks = (const int*)  d_in[2];   // [8,256,256]
    float* out = (float*)d_out;                   // [21,256]

    float* Wmap     = (float*)d_ws;                       // 688,128 floats
    float* partial  = Wmap + (size_t)BB * KC * SRC;       // 1,376,256 floats
    float* partialw = partial + (size_t)BB * CH * KC * CC;// 5,376 floats

    hipMemsetAsync(Wmap, 0, (size_t)BB * KC * SRC * sizeof(float), stream);
    hipMemsetAsync(out, 0, (size_t)KC * CC * sizeof(float), stream);

    p1_classify_scatter<<<(BB * HWP / 4) / 256, 256, 0, stream>>>(preds, masks, Wmap);
    p2_contract<<<dim3(CH, BB), 256, 0, stream>>>(feats, Wmap, partial, partialw);
    p3_finalize<<<dim3(KC, BB), 256, 0, stream>>>(partial, partialw, out);
}

// Round 3
// 52.318 us; speedup vs baseline: 1.8276x; 1.0528x over previous
//
#include <hip/hip_runtime.h>

#define KC   21      // num classes
#define BB   8       // batch
#define CC   256     // feat channels
#define HWP  65536   // 256*256 output pixels per image
#define SRC  4096    // 64*64 source pixels
#define CH2  64      // p-chunks of 64
#define LDF  66      // padded fs row stride (floats): bank = (2c+p)%32 -> 2-way (free)

// d_ws float layout: [0..255] counts | [256..43263] accb[B][K][C] | [43264..] Wmap[B][K][SRC]
#define WS_COUNTS 0
#define WS_ACCB   256
#define WS_WMAP   (256 + BB*KC*CC)           // 43264
#define WS_ZTOT   (WS_WMAP + BB*KC*SRC)      // 731392 floats (= 182848 float4)

__global__ __launch_bounds__(256)
void p0_zero(float* ws) {
    int i = blockIdx.x * 256 + threadIdx.x;
    if (i < WS_ZTOT / 4)
        *reinterpret_cast<float4*>(ws + i * 4) = make_float4(0.f, 0.f, 0.f, 0.f);
}

// ---- Phase 1: argmax + gt-match -> bilinear-weight scatter + exact counts ----
__global__ __launch_bounds__(256)
void p1_classify_scatter(const float* __restrict__ preds,
                         const int*   __restrict__ masks,
                         float* __restrict__ Wmap,     // [B][K][SRC]
                         float* __restrict__ counts)   // [B][K]
{
    __shared__ float hist[KC];
    int tid = threadIdx.x;
    if (tid < KC) hist[tid] = 0.f;
    __syncthreads();

    int idx = blockIdx.x * 256 + tid;            // over B*HWP/4 = 131072
    int b   = idx >> 14;                         // block-uniform (64 blocks / image)
    int hw4 = (idx & 16383) << 2;

    const float* pb = preds + (size_t)b * KC * HWP + hw4;
    float4 v[KC];
#pragma unroll
    for (int k = 0; k < KC; ++k)
        v[k] = *reinterpret_cast<const float4*>(pb + (size_t)k * HWP);

    int4 mm = *reinterpret_cast<const int4*>(masks + b * HWP + hw4);

    float bx = v[0].x, by = v[0].y, bz = v[0].z, bw = v[0].w;
    int   ix = 0, iy = 0, iz = 0, iw = 0;
#pragma unroll
    for (int k = 1; k < KC; ++k) {
        if (v[k].x > bx) { bx = v[k].x; ix = k; }
        if (v[k].y > by) { by = v[k].y; iy = k; }
        if (v[k].z > bz) { bz = v[k].z; iz = k; }
        if (v[k].w > bw) { bw = v[k].w; iw = k; }
    }

    int m[4]  = { mm.x, mm.y, mm.z, mm.w };
    int am[4] = { ix, iy, iz, iw };
#pragma unroll
    for (int j = 0; j < 4; ++j) {
        int mv = m[j];
        if (mv == am[j] && (unsigned)mv < KC) {
            int hw = hw4 + j;
            int h = hw >> 8, w = hw & 255;
            float sy = h * 0.25f - 0.375f;       // half-pixel bilinear at 4x
            float sx = w * 0.25f - 0.375f;
            int y0 = (int)floorf(sy), x0 = (int)floorf(sx);
            float wy = sy - (float)y0, wx = sx - (float)x0;
            int y0c = y0 < 0 ? 0 : y0;
            int y1c = y0 + 1 > 63 ? 63 : y0 + 1;
            int x0c = x0 < 0 ? 0 : x0;
            int x1c = x0 + 1 > 63 ? 63 : x0 + 1;
            float* Wb = Wmap + (size_t)(b * KC + mv) * SRC;
            atomicAdd(&Wb[y0c * 64 + x0c], (1.f - wy) * (1.f - wx));
            atomicAdd(&Wb[y0c * 64 + x1c], (1.f - wy) * wx);
            atomicAdd(&Wb[y1c * 64 + x0c], wy * (1.f - wx));
            atomicAdd(&Wb[y1c * 64 + x1c], wy * wx);
            atomicAdd(&hist[mv], 1.0f);          // integer-valued -> order-exact
        }
    }
    __syncthreads();
    if (tid < KC && hist[tid] != 0.f)
        atomicAdd(&counts[b * KC + tid], hist[tid]);
}

// ---- Phase 2: accb[b,k,c] += sum_{p in chunk} feats[b,c,p] * W[b,k,p] --------
// grid (64 chunks, 8 b) x 512 threads: 2 blocks/CU, 4 waves/SIMD.
// thread = (cp = tid&127 -> channels cp, cp+128 ; psub = tid>>7 -> 16-p window)
__global__ __launch_bounds__(512)
void p2_contract(const float* __restrict__ feats,   // [B][C][SRC]
                 const float* __restrict__ Wmap,    // [B][K][SRC]
                 float* __restrict__ accb)          // [B][K][C]
{
    __shared__ float fs[CC * LDF];    // 67.6 KB
    __shared__ float ws[KC * 64];     // 5.25 KB  (total 72.9 KB -> 2 blocks/CU)
    int chunk = blockIdx.x, b = blockIdx.y;
    int tid = threadIdx.x;
    int p0 = chunk * 64;

    // stage W[21][64]
    for (int t = tid; t < KC * 16; t += 512) {
        int k = t >> 4, pq = t & 15;
        *reinterpret_cast<float4*>(ws + k * 64 + pq * 4) =
            *reinterpret_cast<const float4*>(Wmap + (size_t)(b * KC + k) * SRC + p0 + pq * 4);
    }
    // stage feats[256][64]: 8 float4/thread, 256B-contiguous global rows
    {
        int pq = tid & 15, cb = tid >> 4;        // cb 0..31
#pragma unroll
        for (int i = 0; i < 8; ++i) {
            int c = i * 32 + cb;
            float4 f4 = *reinterpret_cast<const float4*>(
                feats + (size_t)(b * CC + c) * SRC + p0 + pq * 4);
            float* d = fs + c * LDF + pq * 4;    // 8B-aligned, 2-way banks
            *reinterpret_cast<float2*>(d)     = make_float2(f4.x, f4.y);
            *reinterpret_cast<float2*>(d + 2) = make_float2(f4.z, f4.w);
        }
    }
    __syncthreads();

    int cp   = tid & 127;
    int psub = tid >> 7;                          // wave-uniform
    int pw   = psub * 16;
    const float* f0r = fs + cp * LDF + pw;
    const float* f1r = fs + (cp + 128) * LDF + pw;
    const float* wr  = ws + pw;

    float acc0[KC], acc1[KC];
#pragma unroll
    for (int k = 0; k < KC; ++k) { acc0[k] = 0.f; acc1[k] = 0.f; }

#pragma unroll
    for (int q = 0; q < 4; ++q) {
        float2 a01 = *reinterpret_cast<const float2*>(f0r + q * 4);
        float2 a23 = *reinterpret_cast<const float2*>(f0r + q * 4 + 2);
        float2 b01 = *reinterpret_cast<const float2*>(f1r + q * 4);
        float2 b23 = *reinterpret_cast<const float2*>(f1r + q * 4 + 2);
#pragma unroll
        for (int k = 0; k < KC; ++k) {
            float4 w4 = *reinterpret_cast<const float4*>(wr + k * 64 + q * 4); // uniform bcast
            acc0[k] += a01.x * w4.x + a01.y * w4.y + a23.x * w4.z + a23.y * w4.w;
            acc1[k] += b01.x * w4.x + b01.y * w4.y + b23.x * w4.z + b23.y * w4.w;
        }
    }

    // psub 4->1 reduction via LDS scratch overlaid on fs (needs 2*21*256 floats)
    float* scr = fs;
    __syncthreads();
    if (psub >= 2) {
        float* s = scr + (psub - 2) * (KC * CC);
#pragma unroll
        for (int k = 0; k < KC; ++k) {
            s[k * CC + cp]       = acc0[k];
            s[k * CC + cp + 128] = acc1[k];
        }
    }
    __syncthreads();
    if (psub < 2) {
        const float* s = scr + psub * (KC * CC);
#pragma unroll
        for (int k = 0; k < KC; ++k) {
            acc0[k] += s[k * CC + cp];
            acc1[k] += s[k * CC + cp + 128];
        }
    }
    __syncthreads();
    if (psub == 1) {
#pragma unroll
        for (int k = 0; k < KC; ++k) {
            scr[k * CC + cp]       = acc0[k];
            scr[k * CC + cp + 128] = acc1[k];
        }
    }
    __syncthreads();
    if (psub == 0) {
        float* ab = accb + (size_t)(b * KC) * CC;
#pragma unroll
        for (int k = 0; k < KC; ++k) {
            atomicAdd(&ab[k * CC + cp],       acc0[k] + scr[k * CC + cp]);
            atomicAdd(&ab[k * CC + cp + 128], acc1[k] + scr[k * CC + cp + 128]);
        }
    }
}

// ---- Phase 3: normalize + batch-mean (tiny) ---------------------------------
__global__ __launch_bounds__(256)
void p3_finalize(const float* __restrict__ accb,
                 const float* __restrict__ counts,
                 float* __restrict__ out)
{
    int k = blockIdx.x, c = threadIdx.x;
    float acc = 0.f;
#pragma unroll
    for (int b = 0; b < BB; ++b)
        acc += accb[(size_t)(b * KC + k) * CC + c] / (counts[b * KC + k] + 1e-6f);
    out[k * CC + c] = acc * 0.125f;
}

extern "C" void kernel_launch(void* const* d_in, const int* in_sizes, int n_in,
                              void* d_out, int out_size, void* d_ws, size_t ws_size,
                              hipStream_t stream) {
    const float* feats = (const float*)d_in[0];   // [8,256,64,64]
    const float* preds = (const float*)d_in[1];   // [8,21,256,256]
    const int*   masks = (const int*)  d_in[2];   // [8,256,256]
    float* out = (float*)d_out;                   // [21,256]

    float* ws     = (float*)d_ws;
    float* counts = ws + WS_COUNTS;
    float* accb   = ws + WS_ACCB;
    float* Wmap   = ws + WS_WMAP;

    p0_zero<<<(WS_ZTOT / 4 + 255) / 256, 256, 0, stream>>>(ws);
    p1_classify_scatter<<<(BB * HWP / 4) / 256, 256, 0, stream>>>(preds, masks, Wmap, counts);
    p2_contract<<<dim3(CH2, BB), 512, 0, stream>>>(feats, Wmap, accb);
    p3_finalize<<<KC, 256, 0, stream>>>(accb, counts, out);
}